// Round 1
// baseline (281.702 us; speedup 1.0000x reference)
//
#include <hip/hip_runtime.h>
#include <math.h>

#define BLOCK 256
#define SPLIT 4

// ArcMargin constants (match reference)
constexpr float S_    = 30.0f;
constexpr float COS_M = 0.8775825618903728f;   // cos(0.5)
constexpr float SIN_M = 0.4794255386042030f;   // sin(0.5)
constexpr float TH_   = -0.8775825618903728f;  // cos(pi - 0.5)
constexpr float MM_   = 0.2397127693021015f;   // sin(pi - 0.5) * 0.5
constexpr float LOG2E = 1.4426950408889634f;
constexpr float SL2E  = 30.0f * LOG2E;         // S * log2(e)
constexpr float NBIAS = -30.0f * LOG2E;        // fixed shift: exp(S*x - 30) = exp2(x*SL2E + NBIAS)
constexpr float LN2   = 0.6931471805599453f;

// Kernel 1: streaming partial sums of exp(S*x - 30) per row-chunk.
// Fixed shift (max possible logit = S*1 = 30) => partials combine by plain add.
__global__ __launch_bounds__(BLOCK) void partial_kernel(const float* __restrict__ x,
                                                        float* __restrict__ partial,
                                                        int C4, int chunk4) {
    const int row   = blockIdx.y;
    const int chunk = blockIdx.x;
    const long long base = (long long)row * C4 + (long long)chunk * chunk4;
    const float4* __restrict__ xr = (const float4*)x + base;
    int n = C4 - chunk * chunk4;
    if (n > chunk4) n = chunk4;

    float sum = 0.f;
    for (int i = (int)threadIdx.x; i < n; i += BLOCK) {
        float4 v = xr[i];
        sum += __builtin_amdgcn_exp2f(fmaf(v.x, SL2E, NBIAS));
        sum += __builtin_amdgcn_exp2f(fmaf(v.y, SL2E, NBIAS));
        sum += __builtin_amdgcn_exp2f(fmaf(v.z, SL2E, NBIAS));
        sum += __builtin_amdgcn_exp2f(fmaf(v.w, SL2E, NBIAS));
    }

    // wave64 shuffle reduce
    #pragma unroll
    for (int off = 32; off > 0; off >>= 1)
        sum += __shfl_down(sum, off, 64);

    __shared__ float smem[BLOCK / 64];
    const int lane = threadIdx.x & 63;
    const int wid  = threadIdx.x >> 6;
    if (lane == 0) smem[wid] = sum;
    __syncthreads();
    if (threadIdx.x == 0) {
        float s = 0.f;
        #pragma unroll
        for (int w = 0; w < BLOCK / 64; ++w) s += smem[w];
        partial[(long long)row * gridDim.x + chunk] = s;
    }
}

// Kernel 2: per-row combine + target-term swap + LSE + mean. One block.
__global__ __launch_bounds__(512) void finalize_kernel(const float* __restrict__ x,
                                                       const int* __restrict__ target,
                                                       const float* __restrict__ partial,
                                                       float* __restrict__ out,
                                                       int B, long long C, int nchunk) {
    float loss = 0.f;
    for (int b = (int)threadIdx.x; b < B; b += (int)blockDim.x) {
        float s = 0.f;
        for (int k = 0; k < nchunk; ++k) s += partial[(long long)b * nchunk + k];

        const int tgt = target[b];
        const float ct = x[(long long)b * C + tgt];
        const float st = sqrtf(fmaxf(0.f, fmaf(-ct, ct, 1.f)));
        const float phi = ct * COS_M - st * SIN_M;
        const float out_t = S_ * ((ct > TH_) ? phi : (ct - MM_));

        // replace target column's exp(S*cos - 30) with exp(out_t - 30)
        s += __builtin_amdgcn_exp2f(fmaf(out_t, LOG2E, NBIAS))
           - __builtin_amdgcn_exp2f(fmaf(ct, SL2E, NBIAS));

        const float lse = 30.f + __builtin_amdgcn_logf(s) * LN2;  // v_log_f32 = log2
        loss += lse - out_t;
    }

    #pragma unroll
    for (int off = 32; off > 0; off >>= 1)
        loss += __shfl_down(loss, off, 64);

    __shared__ float smem[512 / 64];
    const int lane = threadIdx.x & 63;
    const int wid  = threadIdx.x >> 6;
    if (lane == 0) smem[wid] = loss;
    __syncthreads();
    if (threadIdx.x == 0) {
        float t = 0.f;
        const int nw = (int)blockDim.x >> 6;
        for (int w = 0; w < nw; ++w) t += smem[w];
        out[0] = t / (float)B;
    }
}

extern "C" void kernel_launch(void* const* d_in, const int* in_sizes, int n_in,
                              void* d_out, int out_size, void* d_ws, size_t ws_size,
                              hipStream_t stream) {
    const float* x      = (const float*)d_in[0];
    const int*   target = (const int*)d_in[1];
    float*       out    = (float*)d_out;
    float*       part   = (float*)d_ws;   // B * SPLIT floats (8 KB) << ws_size

    const int B = in_sizes[1];
    const long long total = (long long)in_sizes[0];
    const long long C = total / B;            // 100000
    const int C4 = (int)(C / 4);              // 25000 (C % 4 == 0 for this problem)
    const int chunk4 = (C4 + SPLIT - 1) / SPLIT;

    dim3 grid(SPLIT, B);
    partial_kernel<<<grid, BLOCK, 0, stream>>>(x, part, C4, chunk4);
    finalize_kernel<<<1, 512, 0, stream>>>(x, target, part, out, B, C, SPLIT);
}

// Round 2
// 280.696 us; speedup vs baseline: 1.0036x; 1.0036x over previous
//
#include <hip/hip_runtime.h>
#include <math.h>

// ArcMargin constants (match reference)
constexpr float S_    = 30.0f;
constexpr float COS_M = 0.8775825618903728f;   // cos(0.5)
constexpr float SIN_M = 0.4794255386042030f;   // sin(0.5)
constexpr float TH_   = -0.8775825618903728f;  // cos(pi - 0.5)
constexpr float MM_   = 0.2397127693021015f;   // sin(pi - 0.5) * 0.5
constexpr float LOG2E = 1.4426950408889634f;
constexpr float SL2E  = 30.0f * LOG2E;         // S * log2(e)
constexpr float NBIAS = -30.0f * LOG2E;        // fixed shift: exp(S*x - 30) = exp2(x*SL2E + NBIAS)
constexpr float LN2   = 0.6931471805599453f;

#define TB 1024   // 1024 thr/block, 512 blocks -> 2 blocks/CU, 32 waves/CU (full occupancy)

// One block per row: stream the row, sum exp(S*x - 30), then thread 0 swaps the
// target term (gather is L2-warm: this block just read the whole row) and emits
// the per-row loss  lse - out_t.
__global__ __launch_bounds__(TB) void row_loss_kernel(const float* __restrict__ x,
                                                      const int* __restrict__ target,
                                                      float* __restrict__ row_loss,
                                                      int C4, long long C) {
    const int row = blockIdx.x;
    const float4* __restrict__ xr = (const float4*)x + (long long)row * C4;

    float sum = 0.f;
    for (int i = (int)threadIdx.x; i < C4; i += TB) {
        float4 v = xr[i];
        float e0 = __builtin_amdgcn_exp2f(fmaf(v.x, SL2E, NBIAS));
        float e1 = __builtin_amdgcn_exp2f(fmaf(v.y, SL2E, NBIAS));
        float e2 = __builtin_amdgcn_exp2f(fmaf(v.z, SL2E, NBIAS));
        float e3 = __builtin_amdgcn_exp2f(fmaf(v.w, SL2E, NBIAS));
        sum += (e0 + e1) + (e2 + e3);   // tree adds: shorter dep chain than 4 serial adds
    }

    // wave64 shuffle reduce
    #pragma unroll
    for (int off = 32; off > 0; off >>= 1)
        sum += __shfl_down(sum, off, 64);

    __shared__ float smem[TB / 64];
    const int lane = threadIdx.x & 63;
    const int wid  = threadIdx.x >> 6;
    if (lane == 0) smem[wid] = sum;
    __syncthreads();

    if (threadIdx.x == 0) {
        float s = 0.f;
        #pragma unroll
        for (int w = 0; w < TB / 64; ++w) s += smem[w];

        const int   tgt = target[row];
        const float ct  = x[(long long)row * C + tgt];   // L2-warm gather
        const float st  = sqrtf(fmaxf(0.f, fmaf(-ct, ct, 1.f)));
        const float phi = ct * COS_M - st * SIN_M;
        const float out_t = S_ * ((ct > TH_) ? phi : (ct - MM_));

        // replace target column's exp(S*cos - 30) with exp(out_t - 30)
        s += __builtin_amdgcn_exp2f(fmaf(out_t, LOG2E, NBIAS))
           - __builtin_amdgcn_exp2f(fmaf(ct, SL2E, NBIAS));

        const float lse = 30.f + __builtin_amdgcn_logf(s) * LN2;  // v_log_f32 = log2
        row_loss[row] = lse - out_t;
    }
}

// Mean of B per-row losses -> out[0]. One block, trivial.
__global__ __launch_bounds__(512) void mean_kernel(const float* __restrict__ row_loss,
                                                   float* __restrict__ out, int B) {
    float v = ((int)threadIdx.x < B) ? row_loss[threadIdx.x] : 0.f;

    #pragma unroll
    for (int off = 32; off > 0; off >>= 1)
        v += __shfl_down(v, off, 64);

    __shared__ float smem[512 / 64];
    const int lane = threadIdx.x & 63;
    const int wid  = threadIdx.x >> 6;
    if (lane == 0) smem[wid] = v;
    __syncthreads();
    if (threadIdx.x == 0) {
        float t = 0.f;
        #pragma unroll
        for (int w = 0; w < 512 / 64; ++w) t += smem[w];
        out[0] = t / (float)B;
    }
}

extern "C" void kernel_launch(void* const* d_in, const int* in_sizes, int n_in,
                              void* d_out, int out_size, void* d_ws, size_t ws_size,
                              hipStream_t stream) {
    const float* x      = (const float*)d_in[0];
    const int*   target = (const int*)d_in[1];
    float*       out    = (float*)d_out;
    float*       rloss  = (float*)d_ws;   // B floats (2 KB) << ws_size

    const int B = in_sizes[1];
    const long long total = (long long)in_sizes[0];
    const long long C = total / B;        // 100000
    const int C4 = (int)(C / 4);          // 25000 (C % 4 == 0 here)

    row_loss_kernel<<<B, TB, 0, stream>>>(x, target, rloss, C4, C);
    mean_kernel<<<1, 512, 0, stream>>>(rloss, out, B);
}

// Round 3
// 262.138 us; speedup vs baseline: 1.0746x; 1.0708x over previous
//
#include <hip/hip_runtime.h>
#include <math.h>

#define BLOCK 256
#define SPLIT 4

// ArcMargin constants (match reference)
constexpr float S_    = 30.0f;
constexpr float COS_M = 0.8775825618903728f;   // cos(0.5)
constexpr float SIN_M = 0.4794255386042030f;   // sin(0.5)
constexpr float TH_   = -0.8775825618903728f;  // cos(pi - 0.5)
constexpr float MM_   = 0.2397127693021015f;   // sin(pi - 0.5) * 0.5
constexpr float LOG2E = 1.4426950408889634f;
constexpr float SL2E  = 30.0f * LOG2E;         // S * log2(e)
constexpr float NBIAS = -30.0f * LOG2E;        // fixed shift: exp(S*x - 30) = exp2(x*SL2E + NBIAS)
constexpr float LN2   = 0.6931471805599453f;

typedef float vf4 __attribute__((ext_vector_type(4)));

// Kernel 1: streaming partial sums of exp(S*x - 30) per quarter-row.
// Fixed shift (max logit = S*1 = 30) => partials combine by plain add.
// Non-temporal loads: data is single-use, don't allocate in L2.
__global__ __launch_bounds__(BLOCK) void partial_kernel(const float* __restrict__ x,
                                                        float* __restrict__ partial,
                                                        int C4, int chunk4) {
    const int row   = blockIdx.y;
    const int chunk = blockIdx.x;
    const vf4* __restrict__ xr =
        (const vf4*)x + (long long)row * C4 + (long long)chunk * chunk4;
    int n = C4 - chunk * chunk4;
    if (n > chunk4) n = chunk4;

    float sum = 0.f;
    #pragma unroll 4
    for (int i = (int)threadIdx.x; i < n; i += BLOCK) {
        vf4 v = __builtin_nontemporal_load(xr + i);
        float e0 = __builtin_amdgcn_exp2f(fmaf(v.x, SL2E, NBIAS));
        float e1 = __builtin_amdgcn_exp2f(fmaf(v.y, SL2E, NBIAS));
        float e2 = __builtin_amdgcn_exp2f(fmaf(v.z, SL2E, NBIAS));
        float e3 = __builtin_amdgcn_exp2f(fmaf(v.w, SL2E, NBIAS));
        sum += (e0 + e1) + (e2 + e3);
    }

    // wave64 shuffle reduce
    #pragma unroll
    for (int off = 32; off > 0; off >>= 1)
        sum += __shfl_down(sum, off, 64);

    __shared__ float smem[BLOCK / 64];
    const int lane = threadIdx.x & 63;
    const int wid  = threadIdx.x >> 6;
    if (lane == 0) smem[wid] = sum;
    __syncthreads();
    if (threadIdx.x == 0) {
        float s = 0.f;
        #pragma unroll
        for (int w = 0; w < BLOCK / 64; ++w) s += smem[w];
        partial[(long long)row * gridDim.x + chunk] = s;
    }
}

// Kernel 2: per-row combine + target-term swap + LSE + mean. One block.
__global__ __launch_bounds__(512) void finalize_kernel(const float* __restrict__ x,
                                                       const int* __restrict__ target,
                                                       const float* __restrict__ partial,
                                                       float* __restrict__ out,
                                                       int B, long long C, int nchunk) {
    float loss = 0.f;
    for (int b = (int)threadIdx.x; b < B; b += (int)blockDim.x) {
        float s = 0.f;
        for (int k = 0; k < nchunk; ++k) s += partial[(long long)b * nchunk + k];

        const int   tgt = target[b];
        const float ct  = x[(long long)b * C + tgt];
        const float st  = sqrtf(fmaxf(0.f, fmaf(-ct, ct, 1.f)));
        const float phi = ct * COS_M - st * SIN_M;
        const float out_t = S_ * ((ct > TH_) ? phi : (ct - MM_));

        // replace target column's exp(S*cos - 30) with exp(out_t - 30)
        s += __builtin_amdgcn_exp2f(fmaf(out_t, LOG2E, NBIAS))
           - __builtin_amdgcn_exp2f(fmaf(ct, SL2E, NBIAS));

        const float lse = 30.f + __builtin_amdgcn_logf(s) * LN2;  // v_log_f32 = log2
        loss += lse - out_t;
    }

    #pragma unroll
    for (int off = 32; off > 0; off >>= 1)
        loss += __shfl_down(loss, off, 64);

    __shared__ float smem[512 / 64];
    const int lane = threadIdx.x & 63;
    const int wid  = threadIdx.x >> 6;
    if (lane == 0) smem[wid] = loss;
    __syncthreads();
    if (threadIdx.x == 0) {
        float t = 0.f;
        const int nw = (int)blockDim.x >> 6;
        for (int w = 0; w < nw; ++w) t += smem[w];
        out[0] = t / (float)B;
    }
}

extern "C" void kernel_launch(void* const* d_in, const int* in_sizes, int n_in,
                              void* d_out, int out_size, void* d_ws, size_t ws_size,
                              hipStream_t stream) {
    const float* x      = (const float*)d_in[0];
    const int*   target = (const int*)d_in[1];
    float*       out    = (float*)d_out;
    float*       part   = (float*)d_ws;   // B * SPLIT floats (8 KB) << ws_size

    const int B = in_sizes[1];
    const long long total = (long long)in_sizes[0];
    const long long C = total / B;        // 100000
    const int C4 = (int)(C / 4);          // 25000 (C % 4 == 0 here)
    const int chunk4 = (C4 + SPLIT - 1) / SPLIT;

    dim3 grid(SPLIT, B);
    partial_kernel<<<grid, BLOCK, 0, stream>>>(x, part, C4, chunk4);
    finalize_kernel<<<1, 512, 0, stream>>>(x, target, part, out, B, C, SPLIT);
}

// Round 4
// 258.610 us; speedup vs baseline: 1.0893x; 1.0136x over previous
//
#include <hip/hip_runtime.h>
#include <math.h>

#define BLOCK 256
#define SPLIT 4

// ArcMargin constants (match reference)
constexpr float S_    = 30.0f;
constexpr float COS_M = 0.8775825618903728f;   // cos(0.5)
constexpr float SIN_M = 0.4794255386042030f;   // sin(0.5)
constexpr float TH_   = -0.8775825618903728f;  // cos(pi - 0.5)
constexpr float MM_   = 0.2397127693021015f;   // sin(pi - 0.5) * 0.5
constexpr float LOG2E = 1.4426950408889634f;
constexpr float SL2E  = 30.0f * LOG2E;         // S * log2(e)
constexpr float NBIAS = -30.0f * LOG2E;        // fixed shift: exp(S*x - 30) = exp2(x*SL2E + NBIAS)
constexpr float LN2   = 0.6931471805599453f;

typedef float vf4 __attribute__((ext_vector_type(4)));

// ws layout: [0, B*SPLIT) partial sums, [B*SPLIT, B*SPLIT+B) out_t per row.

// Kernel 1: streaming partial sums of exp(S*x - 30) per quarter-row.
// Fixed shift (max logit = S*1 = 30) => partials combine by plain add.
// Non-temporal loads: data is single-use, don't allocate in L2.
// The chunk owning the target column also folds the margin correction into its
// partial and records out_t — so the finalize kernel never touches x.
__global__ __launch_bounds__(BLOCK) void partial_kernel(const float* __restrict__ x,
                                                        const int* __restrict__ target,
                                                        float* __restrict__ partial,
                                                        float* __restrict__ out_t_arr,
                                                        int C4, int chunk4, long long C) {
    const int row   = blockIdx.y;
    const int chunk = blockIdx.x;
    const vf4* __restrict__ xr =
        (const vf4*)x + (long long)row * C4 + (long long)chunk * chunk4;
    int n = C4 - chunk * chunk4;
    if (n > chunk4) n = chunk4;

    float sum = 0.f;
    #pragma unroll 4
    for (int i = (int)threadIdx.x; i < n; i += BLOCK) {
        vf4 v = __builtin_nontemporal_load(xr + i);
        float e0 = __builtin_amdgcn_exp2f(fmaf(v.x, SL2E, NBIAS));
        float e1 = __builtin_amdgcn_exp2f(fmaf(v.y, SL2E, NBIAS));
        float e2 = __builtin_amdgcn_exp2f(fmaf(v.z, SL2E, NBIAS));
        float e3 = __builtin_amdgcn_exp2f(fmaf(v.w, SL2E, NBIAS));
        sum += (e0 + e1) + (e2 + e3);
    }

    // wave64 shuffle reduce
    #pragma unroll
    for (int off = 32; off > 0; off >>= 1)
        sum += __shfl_down(sum, off, 64);

    __shared__ float smem[BLOCK / 64];
    const int lane = threadIdx.x & 63;
    const int wid  = threadIdx.x >> 6;
    if (lane == 0) smem[wid] = sum;
    __syncthreads();

    if (threadIdx.x == 0) {
        float s = 0.f;
        #pragma unroll
        for (int w = 0; w < BLOCK / 64; ++w) s += smem[w];

        const int tgt = target[row];
        if ((tgt >> 2) / chunk4 == chunk) {   // this chunk owns the target column
            const float ct  = x[(long long)row * C + tgt];
            const float st  = sqrtf(fmaxf(0.f, fmaf(-ct, ct, 1.f)));
            const float phi = ct * COS_M - st * SIN_M;
            const float ot  = S_ * ((ct > TH_) ? phi : (ct - MM_));
            // swap target column's exp(S*cos - 30) -> exp(out_t - 30)
            s += __builtin_amdgcn_exp2f(fmaf(ot, LOG2E, NBIAS))
               - __builtin_amdgcn_exp2f(fmaf(ct, SL2E, NBIAS));
            out_t_arr[row] = ot;
        }
        partial[(long long)row * gridDim.x + chunk] = s;
    }
}

// Kernel 2: combine partials (correction already folded in) + LSE + mean.
// One block, 512 threads = one row each; touches only 12 KB of ws.
__global__ __launch_bounds__(512) void finalize_kernel(const float* __restrict__ partial,
                                                       const float* __restrict__ out_t_arr,
                                                       float* __restrict__ out,
                                                       int B, int nchunk) {
    float loss = 0.f;
    for (int b = (int)threadIdx.x; b < B; b += (int)blockDim.x) {
        float s = 0.f;
        #pragma unroll
        for (int k = 0; k < SPLIT; ++k) s += partial[(long long)b * nchunk + k];
        const float ot  = out_t_arr[b];
        const float lse = 30.f + __builtin_amdgcn_logf(s) * LN2;  // v_log_f32 = log2
        loss += lse - ot;
    }

    #pragma unroll
    for (int off = 32; off > 0; off >>= 1)
        loss += __shfl_down(loss, off, 64);

    __shared__ float smem[512 / 64];
    const int lane = threadIdx.x & 63;
    const int wid  = threadIdx.x >> 6;
    if (lane == 0) smem[wid] = loss;
    __syncthreads();
    if (threadIdx.x == 0) {
        float t = 0.f;
        #pragma unroll
        for (int w = 0; w < 512 / 64; ++w) t += smem[w];
        out[0] = t / (float)B;
    }
}

extern "C" void kernel_launch(void* const* d_in, const int* in_sizes, int n_in,
                              void* d_out, int out_size, void* d_ws, size_t ws_size,
                              hipStream_t stream) {
    const float* x      = (const float*)d_in[0];
    const int*   target = (const int*)d_in[1];
    float*       out    = (float*)d_out;
    float*       part   = (float*)d_ws;            // B * SPLIT floats
    const int B = in_sizes[1];
    float*       ot     = part + (long long)B * SPLIT;  // B floats

    const long long total = (long long)in_sizes[0];
    const long long C = total / B;        // 100000
    const int C4 = (int)(C / 4);          // 25000 (C % 4 == 0 here)
    const int chunk4 = (C4 + SPLIT - 1) / SPLIT;

    dim3 grid(SPLIT, B);
    partial_kernel<<<grid, BLOCK, 0, stream>>>(x, target, part, ot, C4, chunk4, C);
    finalize_kernel<<<1, 512, 0, stream>>>(part, ot, out, B, SPLIT);
}